// Round 6
// baseline (846.991 us; speedup 1.0000x reference)
//
#include <hip/hip_runtime.h>

// LocallyConnectedLayer: out[b,o,i,j] = sum_{c,u,v} x[b,c,i+u,j+v] * w[o,c,i,j,u,v] + bias[o,i,j]
// x: (32,32,64,64) f32, w: (64,32,62,62,3,3) f32, bias: (64,62,62) f32, out: (32,64,62,62) f32
//
// Memory-bound on the 283 MB weight stream (each weight used exactly B=32 times).
// Strategy: all 32 batches held in per-thread register accumulators (16b x 4o tile),
// so every weight is fetched from HBM once. Lanes span j -> coalesced x/out.
// No LDS, no barriers; 992 independent blocks of 128 threads.

#define B_  32
#define C_  32
#define O_  64
#define H_  64
#define W_  64
#define K_  3
#define OH_ 62
#define OW_ 62

__global__ __launch_bounds__(128, 2)
void lcl_fwd(const float* __restrict__ x, const float* __restrict__ w,
             const float* __restrict__ bias, float* __restrict__ out) {
    const int j  = threadIdx.x & 63;     // lane spans output column
    const int bg = threadIdx.x >> 6;     // which b-half (0/1)
    const int i  = blockIdx.y;           // output row
    const int ob = blockIdx.x * 4;       // first of this block's 4 output channels
    const int b0 = bg * 16;
    if (j >= OW_) return;                // 2 idle lanes per wave

    float acc[16][4];
#pragma unroll
    for (int b = 0; b < 16; ++b)
#pragma unroll
        for (int o = 0; o < 4; ++o) acc[b][o] = 0.0f;

    // weights index: ((((o*C + c)*OH + i)*OW + j)*K + u)*K + v
    const int OSTR  = C_ * OH_ * OW_ * K_ * K_;   // o stride   = 1,107,072
    const int CSTRW = OH_ * OW_ * K_ * K_;        // c stride   =    34,596
    const float* wp = w + ((ob * C_ * OH_ + i) * OW_ + j) * (K_ * K_);

    // x index: ((b*C + c)*H + r)*W + col ; r = i+u, col = j+v
    const int BSTRX = C_ * H_ * W_;               // b stride = 131072
    const int CSTRX = H_ * W_;                    // c stride = 4096
    const float* xp = x + ((b0 * C_ + 0) * H_ + i) * W_ + j;

    for (int c = 0; c < C_; ++c) {
        const float* wpc = wp + c * CSTRW;
        const float* xpc = xp + c * CSTRX;
#pragma unroll
        for (int u = 0; u < K_; ++u) {
#pragma unroll
            for (int v = 0; v < K_; ++v) {
                const int wo = u * K_ + v;
                const float wv0 = wpc[0 * OSTR + wo];
                const float wv1 = wpc[1 * OSTR + wo];
                const float wv2 = wpc[2 * OSTR + wo];
                const float wv3 = wpc[3 * OSTR + wo];
                const int xo = u * W_ + v;
#pragma unroll
                for (int b = 0; b < 16; ++b) {
                    const float xv = xpc[b * BSTRX + xo];
                    acc[b][0] = fmaf(xv, wv0, acc[b][0]);
                    acc[b][1] = fmaf(xv, wv1, acc[b][1]);
                    acc[b][2] = fmaf(xv, wv2, acc[b][2]);
                    acc[b][3] = fmaf(xv, wv3, acc[b][3]);
                }
            }
        }
    }

    // epilogue: add bias, store coalesced along j
    const int pos = i * OW_ + j;
    float bz[4];
#pragma unroll
    for (int o = 0; o < 4; ++o) bz[o] = bias[(ob + o) * (OH_ * OW_) + pos];

#pragma unroll
    for (int b = 0; b < 16; ++b) {
#pragma unroll
        for (int o = 0; o < 4; ++o) {
            out[(((b0 + b) * O_ + (ob + o)) * OH_ + i) * OW_ + j] = acc[b][o] + bz[o];
        }
    }
}

extern "C" void kernel_launch(void* const* d_in, const int* in_sizes, int n_in,
                              void* d_out, int out_size, void* d_ws, size_t ws_size,
                              hipStream_t stream) {
    const float* x    = (const float*)d_in[0];
    const float* w    = (const float*)d_in[1];
    const float* bias = (const float*)d_in[2];
    float* out = (float*)d_out;

    dim3 grid(O_ / 4, OH_);   // (16, 62) = 992 blocks
    dim3 block(128);          // 2 waves: the two b-halves
    lcl_fwd<<<grid, block, 0, stream>>>(x, w, bias, out);
}

// Round 7
// 644.812 us; speedup vs baseline: 1.3135x; 1.3135x over previous
//
#include <hip/hip_runtime.h>

// LocallyConnectedLayer: out[b,o,i,j] = sum_{c,u,v} x[b,c,i+u,j+v] * w[o,c,i,j,u,v] + bias[o,i,j]
// x: (32,32,64,64) f32, w: (64,32,62,62,3,3) f32, bias: (64,62,62) f32, out: (32,64,62,62) f32
//
// R6 post-mortem: 16b x 4o register tile spilled (WRITE_SIZE 930 MB vs 31.5 MB output,
// ~900 MB scratch stores + ~330 MB reload fetches -> 1.6 GB total @ 2.8 TB/s = 567 us).
// Fix: 4 waves x 8 batches each, acc[8][4] = 32 VGPRs/thread. The 4 waves share each
// weight line through L1 (9.2 KB/c footprint), so weights still cross HBM exactly once.
// x is L3-resident (16.8 MB). No LDS, no barriers.

#define B_  32
#define C_  32
#define O_  64
#define H_  64
#define W_  64
#define K_  3
#define OH_ 62
#define OW_ 62

__global__ __launch_bounds__(256, 4)
void lcl_fwd(const float* __restrict__ x, const float* __restrict__ w,
             const float* __restrict__ bias, float* __restrict__ out) {
    const int j  = threadIdx.x & 63;     // lane spans output column
    const int wv = threadIdx.x >> 6;     // wave id 0..3 -> batch group
    const int i  = blockIdx.y;           // output row
    const int ob = blockIdx.x * 4;       // this block's 4 output channels
    const int b0 = wv * 8;               // 8 batches per wave
    if (j >= OW_) return;                // lanes 62,63 idle (also guards w OOB)

    float acc[8][4];
#pragma unroll
    for (int b = 0; b < 8; ++b)
#pragma unroll
        for (int o = 0; o < 4; ++o) acc[b][o] = 0.0f;

    // weights index: ((((o*C + c)*OH + i)*OW + j)*K + u)*K + v
    const int OSTR  = C_ * OH_ * OW_ * K_ * K_;   // o stride = 1,107,072
    const int CSTRW = OH_ * OW_ * K_ * K_;        // c stride =    34,596
    const float* wp = w + ((ob * C_ * OH_ + i) * OW_ + j) * (K_ * K_);

    // x index: ((b*C + c)*H + r)*W + col ; r = i+u, col = j+v
    const int BSTRX = C_ * H_ * W_;               // b stride = 131072
    const int CSTRX = H_ * W_;                    // c stride = 4096
    const float* xp = x + ((b0 * C_) * H_ + i) * W_ + j;

    for (int c = 0; c < C_; ++c) {
        const float* wpc = wp + c * CSTRW;
        const float* xpc = xp + c * CSTRX;
#pragma unroll
        for (int u = 0; u < K_; ++u) {
#pragma unroll
            for (int v = 0; v < K_; ++v) {
                const int wo = u * K_ + v;
                const float wv0 = wpc[0 * OSTR + wo];
                const float wv1 = wpc[1 * OSTR + wo];
                const float wv2 = wpc[2 * OSTR + wo];
                const float wv3 = wpc[3 * OSTR + wo];
                const int xo = u * W_ + v;
#pragma unroll
                for (int b = 0; b < 8; ++b) {
                    const float xv = xpc[b * BSTRX + xo];
                    acc[b][0] = fmaf(xv, wv0, acc[b][0]);
                    acc[b][1] = fmaf(xv, wv1, acc[b][1]);
                    acc[b][2] = fmaf(xv, wv2, acc[b][2]);
                    acc[b][3] = fmaf(xv, wv3, acc[b][3]);
                }
            }
        }
    }

    // epilogue: add bias, store coalesced along j
    const int pos = i * OW_ + j;
    float bz[4];
#pragma unroll
    for (int o = 0; o < 4; ++o) bz[o] = bias[(ob + o) * (OH_ * OW_) + pos];

#pragma unroll
    for (int b = 0; b < 8; ++b) {
#pragma unroll
        for (int o = 0; o < 4; ++o) {
            out[(((b0 + b) * O_ + (ob + o)) * OH_ + i) * OW_ + j] = acc[b][o] + bz[o];
        }
    }
}

extern "C" void kernel_launch(void* const* d_in, const int* in_sizes, int n_in,
                              void* d_out, int out_size, void* d_ws, size_t ws_size,
                              hipStream_t stream) {
    const float* x    = (const float*)d_in[0];
    const float* w    = (const float*)d_in[1];
    const float* bias = (const float*)d_in[2];
    float* out = (float*)d_out;

    dim3 grid(O_ / 4, OH_);   // (16, 62) = 992 blocks
    dim3 block(256);          // 4 waves = 4 batch groups sharing weight lines in L1
    lcl_fwd<<<grid, block, 0, stream>>>(x, w, bias, out);
}